// Round 7
// baseline (117.868 us; speedup 1.0000x reference)
//
#include <hip/hip_runtime.h>

// FocusingLoss forward, single fused kernel. B*WL=128 images of 512x512 fp32.
// Stream body (UNCHANGED from R6, which hit ~6.0 TB/s combined read):
//   one pass over pred+tgt (268 MB) staged through LDS via global_load_lds
//   (16B) with counted-vmcnt double-buffered pipeline (raw s_barrier, never
//   vmcnt(0) mid-loop). 8 partial moments {ts,ty,tx,mse,m0,my,mx,m2}/block.
//   spread = m2 - 2cy*my - 2cx*mx + (cy^2+cx^2)*m0 (centroid-independent).
// Fused tail (R5-proven ticket pattern): last block per image reduces the 8
//   partials, computes centroid + disc-window focus sum (L3-hot), emits
//   per-image {loss_term, mse}; last of the 128 finishers sums and writes out.
// One real kernel + one 516-byte memset -> no separate focus/final launches.

#define HH 512
#define WW 512
#define IMG_PIX (HH * WW)                       // 262144
#define VEC_PER_IMG (IMG_PIX / 4)               // 65536 float4
#define BLOCKS_PER_IMG 8
#define VPB (VEC_PER_IMG / BLOCKS_PER_IMG)      // 8192 float4 per array per block
#define THREADS 256
#define TILE_V 512                              // float4 per array per tile (8KB)
#define NTILE (VPB / TILE_V)                    // 16 tiles
#define NIMG 128
#define EPSF 1e-8f
#define R2 400.0f

typedef float f4 __attribute__((ext_vector_type(4)));

__device__ __forceinline__ float wave_reduce_sum(float v) {
    v += __shfl_down(v, 32);
    v += __shfl_down(v, 16);
    v += __shfl_down(v, 8);
    v += __shfl_down(v, 4);
    v += __shfl_down(v, 2);
    v += __shfl_down(v, 1);
    return v;
}

__device__ __forceinline__ double wave_reduce_sum_d(double v) {
    v += __shfl_down(v, 32);
    v += __shfl_down(v, 16);
    v += __shfl_down(v, 8);
    v += __shfl_down(v, 4);
    v += __shfl_down(v, 2);
    v += __shfl_down(v, 1);
    return v;
}

// async global->LDS, 16B per lane; LDS dest = wave-uniform base + lane*16
__device__ __forceinline__ void gl16(const f4* g, f4* l) {
    __builtin_amdgcn_global_load_lds(
        (const __attribute__((address_space(1))) void*)g,
        (__attribute__((address_space(3))) void*)l, 16, 0, 0);
}

// part[block*8+k], k: 0:ts 1:ty 2:tx 3:mse 4:m0 5:my 6:mx 7:m2
// cnt[0..127]: per-image tickets; cnt[128]: global finisher ticket
__global__ void __launch_bounds__(THREADS) fused_kernel(
        const f4* __restrict__ pred, const f4* __restrict__ tgt,
        float* __restrict__ part, unsigned* __restrict__ cnt,
        double* __restrict__ vout, double* __restrict__ mout,
        float* __restrict__ out, double inv_n) {
    __shared__ f4 bufT[2][TILE_V];
    __shared__ f4 bufP[2][TILE_V];

    const int tid  = threadIdx.x;
    const int w    = tid >> 6, lane = tid & 63;
    const int blk  = blockIdx.x;
    const int img  = blk / BLOCKS_PER_IMG;
    const int sub  = blk & (BLOCKS_PER_IMG - 1);
    const int gb0  = blk * VPB;                 // global f4 base of block span
    const int ivb  = sub * VPB;                 // within-image f4 base
    const int o0   = w * 128, o1 = o0 + 64;     // wave's stage chunks

    float ts = 0.f, ty = 0.f, tx = 0.f, mse = 0.f;
    float m0 = 0.f, my = 0.f, mx = 0.f, m2 = 0.f;

    // prologue: stage tile 0 into buffer 0
    gl16(&tgt [gb0 + o0 + lane], &bufT[0][o0]);
    gl16(&tgt [gb0 + o1 + lane], &bufT[0][o1]);
    gl16(&pred[gb0 + o0 + lane], &bufP[0][o0]);
    gl16(&pred[gb0 + o1 + lane], &bufP[0][o1]);

    for (int t = 0; t < NTILE; ++t) {
        // (a) all waves done reading buf[(t+1)&1] from tile t-1
        asm volatile("s_waitcnt lgkmcnt(0)" ::: "memory");
        __builtin_amdgcn_s_barrier();
        __builtin_amdgcn_sched_barrier(0);
        if (t + 1 < NTILE) {
            const int d  = (t + 1) & 1;
            const int gb = gb0 + (t + 1) * TILE_V;
            gl16(&tgt [gb + o0 + lane], &bufT[d][o0]);
            gl16(&tgt [gb + o1 + lane], &bufT[d][o1]);
            gl16(&pred[gb + o0 + lane], &bufP[d][o0]);
            gl16(&pred[gb + o1 + lane], &bufP[d][o1]);
            asm volatile("s_waitcnt vmcnt(4)" ::: "memory");  // tile t landed (mine)
        } else {
            asm volatile("s_waitcnt vmcnt(0)" ::: "memory");
        }
        // (b) everyone's tile-t loads visible
        __builtin_amdgcn_s_barrier();
        __builtin_amdgcn_sched_barrier(0);

        const int d = t & 1;
#pragma unroll
        for (int u = 0; u < TILE_V / THREADS; ++u) {       // 2
            const int pos = u * THREADS + tid;
            const f4 tv = bufT[d][pos];
            const f4 pv = bufP[d][pos];
            const int iv = ivb + t * TILE_V + pos;         // within-image f4 idx
            const float y  = (float)(iv >> 7);             // 128 f4 per row
            const float x0 = (float)((iv & 127) << 2);

            const float tsum = tv[0] + tv[1] + tv[2] + tv[3];
            const float tw1  = tv[1] + 2.f * tv[2] + 3.f * tv[3];
            ts += tsum;
            ty += y * tsum;
            tx += x0 * tsum + tw1;

            const float d0 = pv[0] - tv[0], d1 = pv[1] - tv[1],
                        d2 = pv[2] - tv[2], d3 = pv[3] - tv[3];
            mse += d0 * d0 + d1 * d1 + d2 * d2 + d3 * d3;

            const float psum = pv[0] + pv[1] + pv[2] + pv[3];
            const float pw1  = pv[1] + 2.f * pv[2] + 3.f * pv[3];
            const float pw2  = pv[1] + 4.f * pv[2] + 9.f * pv[3];
            m0 += psum;
            my += y * psum;
            mx += x0 * psum + pw1;
            m2 += (y * y + x0 * x0) * psum + 2.f * x0 * pw1 + pw2;
        }
    }

    float vals[8] = {ts, ty, tx, mse, m0, my, mx, m2};
    __shared__ float red[4][8];
#pragma unroll
    for (int k = 0; k < 8; ++k) vals[k] = wave_reduce_sum(vals[k]);
    if (lane == 0)
#pragma unroll
        for (int k = 0; k < 8; ++k) red[w][k] = vals[k];
    __syncthreads();
    if (tid < 8) {
        part[blk * 8 + tid] = red[0][tid] + red[1][tid] + red[2][tid] + red[3][tid];
        __threadfence();   // release partials before ticket
    }
    __syncthreads();

    __shared__ bool amLast;
    if (tid == 0)
        amLast = (atomicAdd(&cnt[img], 1u) == BLOCKS_PER_IMG - 1);
    __syncthreads();
    if (!amLast) return;
    __threadfence();       // acquire: see all 8 blocks' partials

    // ---- per-image finish (last block of this image) ----
    __shared__ float mom[8];
    {
        float v[8] = {0.f, 0.f, 0.f, 0.f, 0.f, 0.f, 0.f, 0.f};
        if (tid < BLOCKS_PER_IMG) {
            const float* p = part + (img * BLOCKS_PER_IMG + tid) * 8;
#pragma unroll
            for (int k = 0; k < 8; ++k) v[k] = p[k];
        }
        if (tid < 64) {
#pragma unroll
            for (int k = 0; k < 8; ++k) v[k] = wave_reduce_sum(v[k]);
            if (tid == 0)
#pragma unroll
                for (int k = 0; k < 8; ++k) mom[k] = v[k];
        }
    }
    __syncthreads();

    const float tsum = mom[0];
    float fe = 0.f;
    if (tsum >= EPSF) {
        const float cy = mom[1] / tsum;
        const float cx = mom[2] / tsum;
        const int ylo = max(0, (int)ceilf(cy - 20.f) - 1);
        const int yhi = min(HH - 1, (int)floorf(cy + 20.f) + 1);
        const int xlo = max(0, (int)ceilf(cx - 20.f) - 1);
        const int xhi = min(WW - 1, (int)floorf(cx + 20.f) + 1);
        const float* p = (const float*)pred + (size_t)img * IMG_PIX;
        const int wv = tid >> 6;                // wave -> row stripe
        const int xx = xlo + (tid & 63);        // lane -> column
        if (xx <= xhi) {
            const float dx = (float)xx - cx;
            const float dx2 = dx * dx;
            for (int y = ylo + wv; y <= yhi; y += 4) {
                const float dy = (float)y - cy;
                if (dy * dy + dx2 <= R2) fe += p[(y << 9) + xx];
            }
        }
    }
    __shared__ float redf[4];
    fe = wave_reduce_sum(fe);
    if ((tid & 63) == 0) redf[tid >> 6] = fe;
    __syncthreads();

    __shared__ bool amFinal;
    if (tid == 0) {
        const float fet = redf[0] + redf[1] + redf[2] + redf[3];
        const float pm0 = mom[4];
        double v = 0.0;
        if (tsum >= EPSF && pm0 > EPSF) {
            const double dcy = (double)mom[1] / (double)tsum;
            const double dcx = (double)mom[2] / (double)tsum;
            const double spread = (double)mom[7] - 2.0 * dcy * (double)mom[5]
                                - 2.0 * dcx * (double)mom[6]
                                + (dcy * dcy + dcx * dcx) * (double)pm0;
            const double r = 1.0 - (double)fet / (double)pm0;
            v = 10.0 * r * r + spread / (double)pm0;
        }
        vout[img] = v;
        mout[img] = (double)mom[3];
        __threadfence();   // release per-image results before global ticket
        amFinal = (atomicAdd(&cnt[NIMG], 1u) == NIMG - 1);
    }
    __syncthreads();
    if (!amFinal) return;
    __threadfence();       // acquire: see all 128 images' results

    // ---- global finish (exactly one block reaches here) ----
    if (tid < 64) {
        double v = vout[tid] + vout[tid + 64];
        double m = mout[tid] + mout[tid + 64];
        v = wave_reduce_sum_d(v);
        m = wave_reduce_sum_d(m);
        if (tid == 0) out[0] = (float)(m * inv_n + v);
    }
}

extern "C" void kernel_launch(void* const* d_in, const int* in_sizes, int n_in,
                              void* d_out, int out_size, void* d_ws, size_t ws_size,
                              hipStream_t stream) {
    const float* pred = (const float*)d_in[0];
    const float* tgt  = (const float*)d_in[1];
    float* out = (float*)d_out;

    const int n = in_sizes[0];                 // 33554432
    const int nblk = NIMG * BLOCKS_PER_IMG;    // 1024

    // ws: part (nblk*8 f32 = 32 KB) | cnt (129 u32) | vout,mout (128 doubles each)
    float*    part = (float*)d_ws;
    unsigned* cnt  = (unsigned*)((char*)d_ws + 32768);
    double*   vout = (double*)((char*)d_ws + 34816);
    double*   mout = vout + NIMG;

    hipMemsetAsync(cnt, 0, (NIMG + 1) * sizeof(unsigned), stream);
    fused_kernel<<<nblk, THREADS, 0, stream>>>(
        (const f4*)pred, (const f4*)tgt, part, cnt, vout, mout, out,
        1.0 / (double)n);
}

// Round 8
// 54.475 us; speedup vs baseline: 2.1637x; 2.1637x over previous
//
#include <hip/hip_runtime.h>

// FocusingLoss forward. B*WL=128 images of 512x512 fp32.
// stream_kernel (UNCHANGED R6 body, ~6.0 TB/s combined read):
//   one pass over pred+tgt (268 MB) staged through LDS via global_load_lds
//   (16B) with counted-vmcnt double-buffered pipeline (raw s_barrier, never
//   vmcnt(0) mid-loop). 8 partial moments {ts,ty,tx,mse,m0,my,mx,m2}/block.
//   spread = m2 - 2cy*my - 2cx*mx + (cy^2+cx^2)*m0 (centroid-independent).
//   Block 0 additionally zeroes the ticket counter for the tail kernel
//   (kernel boundary makes it visible; saves a memset dispatch).
// focus_final_kernel: 128 blocks (one per image): reduce partials, centroid,
//   disc-window focus sum (L3-hot); LAST finisher (ticket) sums 128 images
//   and writes out[0]. Fences live only in this tiny kernel -- R7 showed
//   agent-scope fences inside the streaming kernel invalidate L2 under
//   concurrent streams and halve bandwidth.

#define HH 512
#define WW 512
#define IMG_PIX (HH * WW)                       // 262144
#define VEC_PER_IMG (IMG_PIX / 4)               // 65536 float4
#define BLOCKS_PER_IMG 8
#define VPB (VEC_PER_IMG / BLOCKS_PER_IMG)      // 8192 float4 per array per block
#define THREADS 256
#define TILE_V 512                              // float4 per array per tile (8KB)
#define NTILE (VPB / TILE_V)                    // 16 tiles
#define NIMG 128
#define EPSF 1e-8f
#define R2 400.0f

typedef float f4 __attribute__((ext_vector_type(4)));

__device__ __forceinline__ float wave_reduce_sum(float v) {
    v += __shfl_down(v, 32);
    v += __shfl_down(v, 16);
    v += __shfl_down(v, 8);
    v += __shfl_down(v, 4);
    v += __shfl_down(v, 2);
    v += __shfl_down(v, 1);
    return v;
}

__device__ __forceinline__ double wave_reduce_sum_d(double v) {
    v += __shfl_down(v, 32);
    v += __shfl_down(v, 16);
    v += __shfl_down(v, 8);
    v += __shfl_down(v, 4);
    v += __shfl_down(v, 2);
    v += __shfl_down(v, 1);
    return v;
}

// async global->LDS, 16B per lane; LDS dest = wave-uniform base + lane*16
__device__ __forceinline__ void gl16(const f4* g, f4* l) {
    __builtin_amdgcn_global_load_lds(
        (const __attribute__((address_space(1))) void*)g,
        (__attribute__((address_space(3))) void*)l, 16, 0, 0);
}

// part[block*8+k], k: 0:ts 1:ty 2:tx 3:mse 4:m0 5:my 6:mx 7:m2
__global__ void __launch_bounds__(THREADS) stream_kernel(
        const f4* __restrict__ pred, const f4* __restrict__ tgt,
        float* __restrict__ part, unsigned* __restrict__ cnt) {
    __shared__ f4 bufT[2][TILE_V];
    __shared__ f4 bufP[2][TILE_V];

    const int tid  = threadIdx.x;
    const int w    = tid >> 6, lane = tid & 63;
    const int blk  = blockIdx.x;
    const int sub  = blk & (BLOCKS_PER_IMG - 1);
    const int gb0  = blk * VPB;                 // global f4 base of block span
    const int ivb  = sub * VPB;                 // within-image f4 base
    const int o0   = w * 128, o1 = o0 + 64;     // wave's stage chunks

    if (blk == 0 && tid == 0) cnt[0] = 0u;      // ticket reset for tail kernel

    float ts = 0.f, ty = 0.f, tx = 0.f, mse = 0.f;
    float m0 = 0.f, my = 0.f, mx = 0.f, m2 = 0.f;

    // prologue: stage tile 0 into buffer 0
    gl16(&tgt [gb0 + o0 + lane], &bufT[0][o0]);
    gl16(&tgt [gb0 + o1 + lane], &bufT[0][o1]);
    gl16(&pred[gb0 + o0 + lane], &bufP[0][o0]);
    gl16(&pred[gb0 + o1 + lane], &bufP[0][o1]);

    for (int t = 0; t < NTILE; ++t) {
        // (a) all waves done reading buf[(t+1)&1] from tile t-1
        asm volatile("s_waitcnt lgkmcnt(0)" ::: "memory");
        __builtin_amdgcn_s_barrier();
        __builtin_amdgcn_sched_barrier(0);
        if (t + 1 < NTILE) {
            const int d  = (t + 1) & 1;
            const int gb = gb0 + (t + 1) * TILE_V;
            gl16(&tgt [gb + o0 + lane], &bufT[d][o0]);
            gl16(&tgt [gb + o1 + lane], &bufT[d][o1]);
            gl16(&pred[gb + o0 + lane], &bufP[d][o0]);
            gl16(&pred[gb + o1 + lane], &bufP[d][o1]);
            asm volatile("s_waitcnt vmcnt(4)" ::: "memory");  // tile t landed (mine)
        } else {
            asm volatile("s_waitcnt vmcnt(0)" ::: "memory");
        }
        // (b) everyone's tile-t loads visible
        __builtin_amdgcn_s_barrier();
        __builtin_amdgcn_sched_barrier(0);

        const int d = t & 1;
#pragma unroll
        for (int u = 0; u < TILE_V / THREADS; ++u) {       // 2
            const int pos = u * THREADS + tid;
            const f4 tv = bufT[d][pos];
            const f4 pv = bufP[d][pos];
            const int iv = ivb + t * TILE_V + pos;         // within-image f4 idx
            const float y  = (float)(iv >> 7);             // 128 f4 per row
            const float x0 = (float)((iv & 127) << 2);

            const float tsum = tv[0] + tv[1] + tv[2] + tv[3];
            const float tw1  = tv[1] + 2.f * tv[2] + 3.f * tv[3];
            ts += tsum;
            ty += y * tsum;
            tx += x0 * tsum + tw1;

            const float d0 = pv[0] - tv[0], d1 = pv[1] - tv[1],
                        d2 = pv[2] - tv[2], d3 = pv[3] - tv[3];
            mse += d0 * d0 + d1 * d1 + d2 * d2 + d3 * d3;

            const float psum = pv[0] + pv[1] + pv[2] + pv[3];
            const float pw1  = pv[1] + 2.f * pv[2] + 3.f * pv[3];
            const float pw2  = pv[1] + 4.f * pv[2] + 9.f * pv[3];
            m0 += psum;
            my += y * psum;
            mx += x0 * psum + pw1;
            m2 += (y * y + x0 * x0) * psum + 2.f * x0 * pw1 + pw2;
        }
    }

    float vals[8] = {ts, ty, tx, mse, m0, my, mx, m2};
    __shared__ float red[4][8];
#pragma unroll
    for (int k = 0; k < 8; ++k) vals[k] = wave_reduce_sum(vals[k]);
    if (lane == 0)
#pragma unroll
        for (int k = 0; k < 8; ++k) red[w][k] = vals[k];
    __syncthreads();
    if (tid < 8)
        part[blk * 8 + tid] = red[0][tid] + red[1][tid] + red[2][tid] + red[3][tid];
}

// one 256-thread block per image: reduce partials, centroid, disc window sum;
// last finisher (global ticket) sums all images and writes out[0].
__global__ void __launch_bounds__(THREADS) focus_final_kernel(
        const float* __restrict__ pred, const float* __restrict__ part,
        unsigned* __restrict__ cnt, double* __restrict__ vout,
        double* __restrict__ mout, float* __restrict__ out, double inv_n) {
    const int img = blockIdx.x;
    const int tid = threadIdx.x;
    __shared__ float mom[8];
    {
        float v[8] = {0.f, 0.f, 0.f, 0.f, 0.f, 0.f, 0.f, 0.f};
        if (tid < BLOCKS_PER_IMG) {
            const float* p = part + (img * BLOCKS_PER_IMG + tid) * 8;
#pragma unroll
            for (int k = 0; k < 8; ++k) v[k] = p[k];
        }
        if (tid < 64) {
#pragma unroll
            for (int k = 0; k < 8; ++k) v[k] = wave_reduce_sum(v[k]);
            if (tid == 0)
#pragma unroll
                for (int k = 0; k < 8; ++k) mom[k] = v[k];
        }
    }
    __syncthreads();

    const float ts = mom[0];
    float fe = 0.f;
    if (ts >= EPSF) {
        const float cy = mom[1] / ts;
        const float cx = mom[2] / ts;
        const int ylo = max(0, (int)ceilf(cy - 20.f) - 1);
        const int yhi = min(HH - 1, (int)floorf(cy + 20.f) + 1);
        const int xlo = max(0, (int)ceilf(cx - 20.f) - 1);
        const int xhi = min(WW - 1, (int)floorf(cx + 20.f) + 1);
        const float* p = pred + (size_t)img * IMG_PIX;
        const int wv = tid >> 6;                // wave -> row stripe
        const int xx = xlo + (tid & 63);        // lane -> column
        if (xx <= xhi) {
            const float dx = (float)xx - cx;
            const float dx2 = dx * dx;
            for (int y = ylo + wv; y <= yhi; y += 4) {
                const float dy = (float)y - cy;
                if (dy * dy + dx2 <= R2) fe += p[(y << 9) + xx];
            }
        }
    }
    __shared__ float redf[4];
    fe = wave_reduce_sum(fe);
    if ((tid & 63) == 0) redf[tid >> 6] = fe;
    __syncthreads();

    __shared__ bool amFinal;
    if (tid == 0) {
        const float fet = redf[0] + redf[1] + redf[2] + redf[3];
        const float m0 = mom[4];
        double v = 0.0;
        if (ts >= EPSF && m0 > EPSF) {
            const double dcy = (double)mom[1] / (double)ts;
            const double dcx = (double)mom[2] / (double)ts;
            const double spread = (double)mom[7] - 2.0 * dcy * (double)mom[5]
                                - 2.0 * dcx * (double)mom[6]
                                + (dcy * dcy + dcx * dcx) * (double)m0;
            const double r = 1.0 - (double)fet / (double)m0;
            v = 10.0 * r * r + spread / (double)m0;
        }
        vout[img] = v;
        mout[img] = (double)mom[3];
        __threadfence();   // release per-image results before ticket
        amFinal = (atomicAdd(&cnt[0], 1u) == NIMG - 1);
    }
    __syncthreads();
    if (!amFinal) return;
    __threadfence();       // acquire: see all 128 images' results

    if (tid < 64) {
        double v = vout[tid] + vout[tid + 64];
        double m = mout[tid] + mout[tid + 64];
        v = wave_reduce_sum_d(v);
        m = wave_reduce_sum_d(m);
        if (tid == 0) out[0] = (float)(m * inv_n + v);
    }
}

extern "C" void kernel_launch(void* const* d_in, const int* in_sizes, int n_in,
                              void* d_out, int out_size, void* d_ws, size_t ws_size,
                              hipStream_t stream) {
    const float* pred = (const float*)d_in[0];
    const float* tgt  = (const float*)d_in[1];
    float* out = (float*)d_out;

    const int n = in_sizes[0];                 // 33554432
    const int nblk = NIMG * BLOCKS_PER_IMG;    // 1024

    // ws: part (nblk*8 f32 = 32 KB) | cnt (1 u32, padded) | vout,mout (doubles)
    float*    part = (float*)d_ws;
    unsigned* cnt  = (unsigned*)((char*)d_ws + 32768);
    double*   vout = (double*)((char*)d_ws + 33024);
    double*   mout = vout + NIMG;

    stream_kernel<<<nblk, THREADS, 0, stream>>>(
        (const f4*)pred, (const f4*)tgt, part, cnt);
    focus_final_kernel<<<NIMG, THREADS, 0, stream>>>(
        pred, part, cnt, vout, mout, out, 1.0 / (double)n);
}

// Round 9
// 51.890 us; speedup vs baseline: 2.2715x; 1.0498x over previous
//
#include <hip/hip_runtime.h>

// FocusingLoss forward. B*WL=128 images of 512x512 fp32.  [R6 best: 52.0 us]
// stream_kernel: one pass over pred+tgt (268 MB) staged through LDS via
//   global_load_lds (16B) with a counted-vmcnt double-buffered pipeline
//   (raw s_barrier, never vmcnt(0) mid-loop). ~6.0 TB/s combined read =
//   ~95% of the 6.29 TB/s measured achievable ceiling. No device-scope
//   fences here (R7: fences in a streaming kernel invalidate L2 -> 2x slow).
//   Per block: 8 partial moments {ts,ty,tx,mse,m0,my,mx,m2} -> unique slot.
//   spread = m2 - 2cy*my - 2cx*mx + (cy^2+cx^2)*m0 (centroid-independent).
// focus_kernel: per-image block: reduce partials, centroid, disc-window sum.
// final_kernel: 128-double sum.

#define HH 512
#define WW 512
#define IMG_PIX (HH * WW)                       // 262144
#define VEC_PER_IMG (IMG_PIX / 4)               // 65536 float4
#define BLOCKS_PER_IMG 8
#define VPB (VEC_PER_IMG / BLOCKS_PER_IMG)      // 8192 float4 per array per block
#define THREADS 256
#define TILE_V 512                              // float4 per array per tile (8KB)
#define NT (VPB / TILE_V)                       // 16 tiles
#define EPSF 1e-8f
#define R2 400.0f

typedef float f4 __attribute__((ext_vector_type(4)));

__device__ __forceinline__ float wave_reduce_sum(float v) {
    v += __shfl_down(v, 32);
    v += __shfl_down(v, 16);
    v += __shfl_down(v, 8);
    v += __shfl_down(v, 4);
    v += __shfl_down(v, 2);
    v += __shfl_down(v, 1);
    return v;
}

__device__ __forceinline__ double wave_reduce_sum_d(double v) {
    v += __shfl_down(v, 32);
    v += __shfl_down(v, 16);
    v += __shfl_down(v, 8);
    v += __shfl_down(v, 4);
    v += __shfl_down(v, 2);
    v += __shfl_down(v, 1);
    return v;
}

// async global->LDS, 16B per lane; LDS dest = wave-uniform base + lane*16
__device__ __forceinline__ void gl16(const f4* g, f4* l) {
    __builtin_amdgcn_global_load_lds(
        (const __attribute__((address_space(1))) void*)g,
        (__attribute__((address_space(3))) void*)l, 16, 0, 0);
}

// part[block*8+k], k: 0:ts 1:ty 2:tx 3:mse 4:m0 5:my 6:mx 7:m2
__global__ void __launch_bounds__(THREADS) stream_kernel(
        const f4* __restrict__ pred, const f4* __restrict__ tgt,
        float* __restrict__ part) {
    __shared__ f4 bufT[2][TILE_V];
    __shared__ f4 bufP[2][TILE_V];

    const int tid  = threadIdx.x;
    const int w    = tid >> 6, lane = tid & 63;
    const int blk  = blockIdx.x;
    const int sub  = blk & (BLOCKS_PER_IMG - 1);
    const int gb0  = blk * VPB;                 // global f4 base of block span
    const int ivb  = sub * VPB;                 // within-image f4 base
    const int o0   = w * 128, o1 = o0 + 64;     // wave's stage chunks

    float ts = 0.f, ty = 0.f, tx = 0.f, mse = 0.f;
    float m0 = 0.f, my = 0.f, mx = 0.f, m2 = 0.f;

    // prologue: stage tile 0 into buffer 0 (4 gloads, 4KB in flight per wave)
    gl16(&tgt [gb0 + o0 + lane], &bufT[0][o0]);
    gl16(&tgt [gb0 + o1 + lane], &bufT[0][o1]);
    gl16(&pred[gb0 + o0 + lane], &bufP[0][o0]);
    gl16(&pred[gb0 + o1 + lane], &bufP[0][o1]);

    for (int t = 0; t < NT; ++t) {
        // (a) all waves done reading buf[(t+1)&1] from tile t-1
        asm volatile("s_waitcnt lgkmcnt(0)" ::: "memory");
        __builtin_amdgcn_s_barrier();
        __builtin_amdgcn_sched_barrier(0);
        if (t + 1 < NT) {
            const int d  = (t + 1) & 1;
            const int gb = gb0 + (t + 1) * TILE_V;
            gl16(&tgt [gb + o0 + lane], &bufT[d][o0]);
            gl16(&tgt [gb + o1 + lane], &bufT[d][o1]);
            gl16(&pred[gb + o0 + lane], &bufP[d][o0]);
            gl16(&pred[gb + o1 + lane], &bufP[d][o1]);
            asm volatile("s_waitcnt vmcnt(4)" ::: "memory");  // tile t landed (mine)
        } else {
            asm volatile("s_waitcnt vmcnt(0)" ::: "memory");
        }
        // (b) everyone's tile-t loads visible
        __builtin_amdgcn_s_barrier();
        __builtin_amdgcn_sched_barrier(0);

        const int d = t & 1;
#pragma unroll
        for (int u = 0; u < TILE_V / THREADS; ++u) {       // 2
            const int pos = u * THREADS + tid;
            const f4 tv = bufT[d][pos];
            const f4 pv = bufP[d][pos];
            const int iv = ivb + t * TILE_V + pos;         // within-image f4 idx
            const float y  = (float)(iv >> 7);             // 128 f4 per row
            const float x0 = (float)((iv & 127) << 2);

            const float tsum = tv[0] + tv[1] + tv[2] + tv[3];
            const float tw1  = tv[1] + 2.f * tv[2] + 3.f * tv[3];
            ts += tsum;
            ty += y * tsum;
            tx += x0 * tsum + tw1;

            const float d0 = pv[0] - tv[0], d1 = pv[1] - tv[1],
                        d2 = pv[2] - tv[2], d3 = pv[3] - tv[3];
            mse += d0 * d0 + d1 * d1 + d2 * d2 + d3 * d3;

            const float psum = pv[0] + pv[1] + pv[2] + pv[3];
            const float pw1  = pv[1] + 2.f * pv[2] + 3.f * pv[3];
            const float pw2  = pv[1] + 4.f * pv[2] + 9.f * pv[3];
            m0 += psum;
            my += y * psum;
            mx += x0 * psum + pw1;
            m2 += (y * y + x0 * x0) * psum + 2.f * x0 * pw1 + pw2;
        }
    }

    float vals[8] = {ts, ty, tx, mse, m0, my, mx, m2};
    __shared__ float red[4][8];
#pragma unroll
    for (int k = 0; k < 8; ++k) vals[k] = wave_reduce_sum(vals[k]);
    if (lane == 0)
#pragma unroll
        for (int k = 0; k < 8; ++k) red[w][k] = vals[k];
    __syncthreads();
    if (tid < 8)
        part[blk * 8 + tid] = red[0][tid] + red[1][tid] + red[2][tid] + red[3][tid];
}

// one 256-thread block per image: reduce partials, centroid, disc window sum,
// emit per-image {loss_term, mse} as doubles.
__global__ void __launch_bounds__(THREADS) focus_kernel(
        const float* __restrict__ pred, const float* __restrict__ part,
        double* __restrict__ vout, double* __restrict__ mout) {
    const int img = blockIdx.x;
    const int tid = threadIdx.x;
    __shared__ float mom[8];
    {
        float v[8] = {0.f, 0.f, 0.f, 0.f, 0.f, 0.f, 0.f, 0.f};
        if (tid < BLOCKS_PER_IMG) {
            const float* p = part + (img * BLOCKS_PER_IMG + tid) * 8;
#pragma unroll
            for (int k = 0; k < 8; ++k) v[k] = p[k];
        }
        if (tid < 64) {
#pragma unroll
            for (int k = 0; k < 8; ++k) v[k] = wave_reduce_sum(v[k]);
            if (tid == 0)
#pragma unroll
                for (int k = 0; k < 8; ++k) mom[k] = v[k];
        }
    }
    __syncthreads();

    const float ts = mom[0];
    float fe = 0.f;
    if (ts >= EPSF) {
        const float cy = mom[1] / ts;
        const float cx = mom[2] / ts;
        const int ylo = max(0, (int)ceilf(cy - 20.f) - 1);
        const int yhi = min(HH - 1, (int)floorf(cy + 20.f) + 1);
        const int xlo = max(0, (int)ceilf(cx - 20.f) - 1);
        const int xhi = min(WW - 1, (int)floorf(cx + 20.f) + 1);
        const float* p = pred + (size_t)img * IMG_PIX;
        const int wv = tid >> 6;                // wave -> row stripe
        const int xx = xlo + (tid & 63);        // lane -> column
        if (xx <= xhi) {
            const float dx = (float)xx - cx;
            const float dx2 = dx * dx;
            for (int y = ylo + wv; y <= yhi; y += 4) {
                const float dy = (float)y - cy;
                if (dy * dy + dx2 <= R2) fe += p[(y << 9) + xx];
            }
        }
    }
    __shared__ float redf[4];
    fe = wave_reduce_sum(fe);
    if ((tid & 63) == 0) redf[tid >> 6] = fe;
    __syncthreads();
    if (tid == 0) {
        const float fet = redf[0] + redf[1] + redf[2] + redf[3];
        const float m0 = mom[4];
        double v = 0.0;
        if (ts >= EPSF && m0 > EPSF) {
            const double dcy = (double)mom[1] / (double)ts;
            const double dcx = (double)mom[2] / (double)ts;
            const double spread = (double)mom[7] - 2.0 * dcy * (double)mom[5]
                                - 2.0 * dcx * (double)mom[6]
                                + (dcy * dcy + dcx * dcx) * (double)m0;
            const double r = 1.0 - (double)fet / (double)m0;
            v = 10.0 * r * r + spread / (double)m0;
        }
        vout[img] = v;
        mout[img] = (double)mom[3];
    }
}

__global__ void __launch_bounds__(128) final_kernel(
        const double* __restrict__ vout, const double* __restrict__ mout,
        float* __restrict__ out, int nimg, double inv_n) {
    const int i = threadIdx.x;
    double v = 0.0, m = 0.0;
    if (i < nimg) { v = vout[i]; m = mout[i]; }
    __shared__ double redv[2], redm[2];
    v = wave_reduce_sum_d(v);
    m = wave_reduce_sum_d(m);
    if ((i & 63) == 0) { redv[i >> 6] = v; redm[i >> 6] = m; }
    __syncthreads();
    if (i == 0)
        out[0] = (float)((redm[0] + redm[1]) * inv_n + redv[0] + redv[1]);
}

extern "C" void kernel_launch(void* const* d_in, const int* in_sizes, int n_in,
                              void* d_out, int out_size, void* d_ws, size_t ws_size,
                              hipStream_t stream) {
    const float* pred = (const float*)d_in[0];
    const float* tgt  = (const float*)d_in[1];
    float* out = (float*)d_out;

    const int n = in_sizes[0];                 // 33554432
    const int nimg = n / IMG_PIX;              // 128
    const int nblk = nimg * BLOCKS_PER_IMG;    // 1024

    float*  part = (float*)d_ws;                         // nblk*8 f32 = 32 KB
    double* vout = (double*)((char*)d_ws + 32768);       // nimg doubles
    double* mout = vout + nimg;                          // nimg doubles
    // every slot rewritten each call -> deterministic, no zeroing needed

    stream_kernel<<<nblk, THREADS, 0, stream>>>(
        (const f4*)pred, (const f4*)tgt, part);
    focus_kernel<<<nimg, THREADS, 0, stream>>>(pred, part, vout, mout);
    final_kernel<<<1, 128, 0, stream>>>(vout, mout, out, nimg, 1.0 / (double)n);
}